// Round 11
// baseline (500.337 us; speedup 1.0000x reference)
//
#include <hip/hip_runtime.h>
#include <hip/hip_bf16.h>
#include <math.h>

// Problem constants
#define N_PTS   6144
#define FEAT    512
#define HID     256
#define KMAX    50
#define KNN     20
#define THR     0.1f
#define CW      1536        // adj column-chunk width (4 chunks of 1536)
#define NCHUNK  4
#define NTILE   12          // 128-col tiles per chunk
#define CXC     64          // coarsening rows per chunk
#define NCHX    (N_PTS / CXC)   // 96 partial chunks

typedef unsigned short u16;
typedef __attribute__((ext_vector_type(8))) short bf16x8;
typedef __attribute__((ext_vector_type(8))) u16   u16x8;
typedef __attribute__((ext_vector_type(4))) float f32x4;

// round-to-nearest-even fp32 -> bf16 (inputs finite)
__device__ __forceinline__ u16 f2bf(float x) {
    union { float f; unsigned u; } a; a.f = x;
    unsigned r = (a.u + 0x7fffu + ((a.u >> 16) & 1u)) >> 16;
    return (u16)r;
}
__device__ __forceinline__ float bf2f(u16 h) {
    union { unsigned u; float f; } a; a.u = ((unsigned)h) << 16;
    return a.f;
}

__device__ __forceinline__ void gload16(const void* g, void* l) {
    __builtin_amdgcn_global_load_lds(
        (const __attribute__((address_space(1))) void*)g,
        (__attribute__((address_space(3))) void*)l, 16, 0, 0);
}

// ---------------------------------------------------------------------------
// init: zero accumulators (ws/d_out are poisoned 0xAA before every launch)
// ---------------------------------------------------------------------------
__global__ void init_kernel(int* __restrict__ indeg, int* __restrict__ fillc,
                            int* __restrict__ ec) {
    int t = blockIdx.x * blockDim.x + threadIdx.x;
    if (t < N_PTS) { indeg[t] = 0; fillc[t] = 0; }
    if (t == 0) { ec[0] = 0; }
}

// ---------------------------------------------------------------------------
// fn = features/||row||; emit bf16 hi/lo of normalized AND raw features
// ---------------------------------------------------------------------------
__global__ __launch_bounds__(64) void normalize_kernel(const float* __restrict__ f,
                                                       u16* __restrict__ fnh,
                                                       u16* __restrict__ fnl,
                                                       u16* __restrict__ fh_,
                                                       u16* __restrict__ fl_) {
    int row = blockIdx.x, lane = threadIdx.x;
    const float4* fr = (const float4*)(f + (size_t)row * FEAT);
    float4 v0 = fr[lane * 2 + 0];
    float4 v1 = fr[lane * 2 + 1];
    float ss = v0.x * v0.x + v0.y * v0.y + v0.z * v0.z + v0.w * v0.w
             + v1.x * v1.x + v1.y * v1.y + v1.z * v1.z + v1.w * v1.w;
#pragma unroll
    for (int m = 1; m < 64; m <<= 1) ss += __shfl_xor(ss, m);
    float nrm = fmaxf(sqrtf(ss), 1e-12f);
    float r[8] = { v0.x, v0.y, v0.z, v0.w, v1.x, v1.y, v1.z, v1.w };
    u16x8 h, l, rh, rl;
#pragma unroll
    for (int q = 0; q < 8; q++) {
        float vn = r[q] / nrm;
        u16 hb = f2bf(vn);
        h[q] = hb; l[q] = f2bf(vn - bf2f(hb));
        u16 rb = f2bf(r[q]);
        rh[q] = rb; rl[q] = f2bf(r[q] - bf2f(rb));
    }
    size_t base = (size_t)row * FEAT + lane * 8;
    *(u16x8*)(fnh + base) = h;
    *(u16x8*)(fnl + base) = l;
    *(u16x8*)(fh_ + base) = rh;
    *(u16x8*)(fl_ + base) = rl;
}

// p2[i] = x^2 + y^2
__global__ void p2_kernel(const float* __restrict__ pos, float* __restrict__ p2) {
    int i = blockIdx.x * blockDim.x + threadIdx.x;
    if (i < N_PTS) {
        float x = pos[2 * i], y = pos[2 * i + 1];
        p2[i] = x * x + y * y;
    }
}

// transpose + split W1 [512][256] -> W1T hi/lo [256][512]
__global__ __launch_bounds__(256) void w1t_split_kernel(const float* __restrict__ W1,
                                                        u16* __restrict__ th,
                                                        u16* __restrict__ tl) {
    int n = blockIdx.x;
    for (int k = threadIdx.x; k < FEAT; k += 256) {
        float v = W1[(size_t)k * HID + n];
        u16 hb = f2bf(v);
        th[(size_t)n * FEAT + k] = hb;
        tl[(size_t)n * FEAT + k] = f2bf(v - bf2f(hb));
    }
}

// transpose + split W2 [256][50] -> W2T hi/lo [64][256] (rows 50..63 zero)
__global__ __launch_bounds__(256) void w2t_split_kernel(const float* __restrict__ W2,
                                                        u16* __restrict__ th,
                                                        u16* __restrict__ tl) {
    int n = blockIdx.x, k = threadIdx.x;
    float v = (n < KMAX) ? W2[(size_t)k * KMAX + n] : 0.f;
    u16 hb = f2bf(v);
    th[(size_t)n * HID + k] = hb;
    tl[(size_t)n * HID + k] = f2bf(v - bf2f(hb));
}

// ---------------------------------------------------------------------------
// LDS swizzle scheme (verified R6: conflicts 2.36M -> 0):
//   LDS tile [R][32]u16, 64B rows of four 16B slots. slot' = slot ^ ((row>>1)&3).
//   Stage keeps LDS dest LINEAR (global_load_lds) and pre-swizzles the GLOBAL
//   source k-slot; ds_read applies the same XOR.
// ---------------------------------------------------------------------------

// ---------------------------------------------------------------------------
// adj chunk via MFMA bf16 hi/lo split, 8 waves/block:
//   sim = Ah.Bh^T + Ah.Bl^T + Al.Bh^T; fused sigmoid/spatial epilogue.
// R11: also emits EXACT per-row max over this block's 128 cols into
//   rtmax[row][tile] (tile = bx), enabling bound-guided topk.
// ---------------------------------------------------------------------------
__global__ __launch_bounds__(512) void gemm_adj_mfma_kernel(
    const u16* __restrict__ fnh, const u16* __restrict__ fnl,
    const float* __restrict__ pos, const float* __restrict__ p2,
    const float* __restrict__ lamw, const float* __restrict__ tempw,
    float* __restrict__ out, float* __restrict__ rtmax, int c0) {
    __shared__ u16 Ah[128 * 32], Al[128 * 32], Bh[128 * 32], Bl[128 * 32];
    __shared__ float rmxs[128][4];
    const int tid  = threadIdx.x;
    const int lane = tid & 63, wid = tid >> 6;
    const int wm = wid >> 2, wn = wid & 3;       // 2x4 wave grid
    // XCD-aware bijective remap: 576 blocks, 72 contiguous per XCD
    const int flat = blockIdx.y * gridDim.x + blockIdx.x;
    const int nwg  = gridDim.x * gridDim.y;
    const int swzb = (flat & 7) * (nwg >> 3) + (flat >> 3);
    const int bx = swzb % gridDim.x, by = swzb / gridDim.x;
    const int bm  = by * 128;                    // global row base
    const int bnl = bx * 128;                    // chunk-local col base
    const int bng = c0 + bnl;                    // global col base

    // staging: wave w covers half (w&1) of buffer (w>>1); 4 issues x 16 rows
    const int sbuf = wid >> 1, shalf = wid & 1;
    const u16* src = (sbuf & 1) ? fnl : fnh;
    u16* dst = (sbuf == 0) ? Ah : (sbuf == 1) ? Al : (sbuf == 2) ? Bh : Bl;
    const int grow = (sbuf >> 1) ? bng : bm;
    const u16* gbase = src + (size_t)(grow + shalf * 64 + (lane >> 2)) * FEAT
                     + (((lane & 3) ^ ((lane >> 3) & 3)) * 8);
    u16* ldst = dst + (shalf * 64) * 32;

    f32x4 acc[4][2];
#pragma unroll
    for (int m = 0; m < 4; m++)
#pragma unroll
        for (int n = 0; n < 2; n++) acc[m][n] = (f32x4){0.f, 0.f, 0.f, 0.f};

    const int fr = lane & 15;     // fragment row/col
    const int ks = lane >> 4;     // k-slot (8 bf16 each)
    const int ksw = (ks ^ ((fr >> 1) & 3)) * 8;  // swizzled slot offset
    const int abase = (wm * 64 + fr) * 32 + ksw;
    const int bbase = (wn * 32 + fr) * 32 + ksw;

    for (int k0 = 0; k0 < FEAT; k0 += 32) {
#pragma unroll
        for (int i = 0; i < 4; i++)
            gload16(gbase + k0 + (size_t)i * 16 * FEAT, ldst + i * 512);
        __syncthreads();
        bf16x8 ahf[4], alf[4], bhf[2], blf[2];
#pragma unroll
        for (int m = 0; m < 4; m++) {
            ahf[m] = *(const bf16x8*)&Ah[abase + m * 16 * 32];
            alf[m] = *(const bf16x8*)&Al[abase + m * 16 * 32];
        }
#pragma unroll
        for (int n = 0; n < 2; n++) {
            bhf[n] = *(const bf16x8*)&Bh[bbase + n * 16 * 32];
            blf[n] = *(const bf16x8*)&Bl[bbase + n * 16 * 32];
        }
#pragma unroll
        for (int m = 0; m < 4; m++)
#pragma unroll
            for (int n = 0; n < 2; n++) {
                acc[m][n] = __builtin_amdgcn_mfma_f32_16x16x32_bf16(ahf[m], bhf[n], acc[m][n], 0, 0, 0);
                acc[m][n] = __builtin_amdgcn_mfma_f32_16x16x32_bf16(ahf[m], blf[n], acc[m][n], 0, 0, 0);
                acc[m][n] = __builtin_amdgcn_mfma_f32_16x16x32_bf16(alf[m], bhf[n], acc[m][n], 0, 0, 0);
            }
        __syncthreads();
    }

    // epilogue: fuse spatial kernel + sigmoid; track per-row max of outputs.
    // C/D layout (16x16x32): col = lane&15, row = (lane>>4)*4 + reg
    float lam  = 1.f / (1.f + __expf(-lamw[0]));
    float temp = tempw[0];
    float p2c[2], pxc[2], pyc[2];
#pragma unroll
    for (int n = 0; n < 2; n++) {
        int cg = bng + wn * 32 + n * 16 + fr;
        p2c[n] = p2[cg]; pxc[n] = pos[2 * cg]; pyc[n] = pos[2 * cg + 1];
    }
#pragma unroll
    for (int m = 0; m < 4; m++) {
#pragma unroll
        for (int reg = 0; reg < 4; reg++) {
            int rrow = bm + wm * 64 + m * 16 + ks * 4 + reg;
            float p2r = p2[rrow], pxr = pos[2 * rrow], pyr = pos[2 * rrow + 1];
            float mx = -INFINITY;
#pragma unroll
            for (int n = 0; n < 2; n++) {
                float sim = acc[m][n][reg];
                float d2 = fmaxf(p2r + p2c[n] - 2.f * (pxr * pxc[n] + pyr * pyc[n]), 0.f);
                float sk = __expf(-d2 * (1.f / 5000.f));
                float arg = (lam * sim + (1.f - lam) * sk) * temp;
                float o = 1.f / (1.f + __expf(-arg));
                out[(size_t)rrow * CW + bnl + wn * 32 + n * 16 + fr] = o;
                mx = fmaxf(mx, o);
            }
            // reduce over the 16-lane fr group (same row set per ks)
#pragma unroll
            for (int msk = 1; msk < 16; msk <<= 1) mx = fmaxf(mx, __shfl_xor(mx, msk));
            if (fr == 0) rmxs[wm * 64 + m * 16 + ks * 4 + reg][wn] = mx;
        }
    }
    __syncthreads();
    if (tid < 128) {
        float v = fmaxf(fmaxf(rmxs[tid][0], rmxs[tid][1]),
                        fmaxf(rmxs[tid][2], rmxs[tid][3]));
        rtmax[(size_t)(bm + tid) * NTILE + bx] = v;
    }
}

// ---------------------------------------------------------------------------
// Z = X @ W1 via MFMA hi/lo split. 128x128 tile, K=512. B = W1T [256][512].
// ---------------------------------------------------------------------------
__global__ __launch_bounds__(256) void gemm_z_kernel(
    const u16* __restrict__ xh, const u16* __restrict__ xl,
    const u16* __restrict__ w1th, const u16* __restrict__ w1tl,
    float* __restrict__ Z) {
    __shared__ u16 Ah[128 * 32], Al[128 * 32], Bh[128 * 32], Bl[128 * 32];
    const int tid  = threadIdx.x;
    const int lane = tid & 63, wid = tid >> 6;
    const int wm = wid >> 1, wn = wid & 1;
    const int flat = blockIdx.y * gridDim.x + blockIdx.x;
    const int nwg  = gridDim.x * gridDim.y;
    const int swzb = (flat & 7) * (nwg >> 3) + (flat >> 3);
    const int bm = (swzb / gridDim.x) * 128;
    const int bn = (swzb % gridDim.x) * 128;

    const u16* src; u16* dst; int grow;
    if      (wid == 0) { src = xh;   dst = Ah; grow = bm; }
    else if (wid == 1) { src = xl;   dst = Al; grow = bm; }
    else if (wid == 2) { src = w1th; dst = Bh; grow = bn; }
    else               { src = w1tl; dst = Bl; grow = bn; }
    const u16* gbase = src + (size_t)(grow + (lane >> 2)) * FEAT
                     + (((lane & 3) ^ ((lane >> 3) & 3)) * 8);

    f32x4 acc[4][4];
#pragma unroll
    for (int m = 0; m < 4; m++)
#pragma unroll
        for (int n = 0; n < 4; n++) acc[m][n] = (f32x4){0.f, 0.f, 0.f, 0.f};

    const int fr = lane & 15;
    const int ks = lane >> 4;
    const int ksw = (ks ^ ((fr >> 1) & 3)) * 8;
    const int abase = (wm * 64 + fr) * 32 + ksw;
    const int bbase = (wn * 64 + fr) * 32 + ksw;

    for (int k0 = 0; k0 < FEAT; k0 += 32) {
#pragma unroll
        for (int i = 0; i < 8; i++)
            gload16(gbase + k0 + (size_t)i * 16 * FEAT, dst + i * 512);
        __syncthreads();
        bf16x8 ahf[4], alf[4], bhf[4], blf[4];
#pragma unroll
        for (int m = 0; m < 4; m++) {
            ahf[m] = *(const bf16x8*)&Ah[abase + m * 16 * 32];
            alf[m] = *(const bf16x8*)&Al[abase + m * 16 * 32];
        }
#pragma unroll
        for (int n = 0; n < 4; n++) {
            bhf[n] = *(const bf16x8*)&Bh[bbase + n * 16 * 32];
            blf[n] = *(const bf16x8*)&Bl[bbase + n * 16 * 32];
        }
#pragma unroll
        for (int m = 0; m < 4; m++)
#pragma unroll
            for (int n = 0; n < 4; n++) {
                acc[m][n] = __builtin_amdgcn_mfma_f32_16x16x32_bf16(ahf[m], bhf[n], acc[m][n], 0, 0, 0);
                acc[m][n] = __builtin_amdgcn_mfma_f32_16x16x32_bf16(ahf[m], blf[n], acc[m][n], 0, 0, 0);
                acc[m][n] = __builtin_amdgcn_mfma_f32_16x16x32_bf16(alf[m], bhf[n], acc[m][n], 0, 0, 0);
            }
        __syncthreads();
    }
#pragma unroll
    for (int m = 0; m < 4; m++)
#pragma unroll
        for (int reg = 0; reg < 4; reg++) {
            int rrow = bm + wm * 64 + m * 16 + ks * 4 + reg;
#pragma unroll
            for (int n = 0; n < 4; n++)
                Z[(size_t)rrow * HID + bn + wn * 64 + n * 16 + fr] = acc[m][n][reg];
        }
}

// ---------------------------------------------------------------------------
// Y = h @ W2 via MFMA hi/lo split. 128x64 tile, K=256. B = W2T [64][256].
// ---------------------------------------------------------------------------
__global__ __launch_bounds__(256) void gemm_y_kernel(
    const u16* __restrict__ hh, const u16* __restrict__ hl,
    const u16* __restrict__ w2th, const u16* __restrict__ w2tl,
    float* __restrict__ Y) {
    __shared__ u16 Ah[128 * 32], Al[128 * 32], Bh[64 * 32], Bl[64 * 32];
    const int tid  = threadIdx.x;
    const int lane = tid & 63, wid = tid >> 6;
    const int wm = wid >> 1, wn = wid & 1;       // wave: 64 rows x 32 cols
    const int bm = blockIdx.x * 128;

    const u16* src; u16* dst; int grow; int nld;
    if      (wid == 0) { src = hh;   dst = Ah; grow = bm; nld = 8; }
    else if (wid == 1) { src = hl;   dst = Al; grow = bm; nld = 8; }
    else if (wid == 2) { src = w2th; dst = Bh; grow = 0;  nld = 4; }
    else               { src = w2tl; dst = Bl; grow = 0;  nld = 4; }
    const u16* gbase = src + (size_t)(grow + (lane >> 2)) * HID
                     + (((lane & 3) ^ ((lane >> 3) & 3)) * 8);

    f32x4 acc[4][2];
#pragma unroll
    for (int m = 0; m < 4; m++)
#pragma unroll
        for (int n = 0; n < 2; n++) acc[m][n] = (f32x4){0.f, 0.f, 0.f, 0.f};

    const int fr = lane & 15;
    const int ks = lane >> 4;
    const int ksw = (ks ^ ((fr >> 1) & 3)) * 8;
    const int abase = (wm * 64 + fr) * 32 + ksw;
    const int bbase = (wn * 32 + fr) * 32 + ksw;

    for (int k0 = 0; k0 < HID; k0 += 32) {
        for (int i = 0; i < nld; i++)
            gload16(gbase + k0 + (size_t)i * 16 * HID, dst + i * 512);
        __syncthreads();
        bf16x8 ahf[4], alf[4], bhf[2], blf[2];
#pragma unroll
        for (int m = 0; m < 4; m++) {
            ahf[m] = *(const bf16x8*)&Ah[abase + m * 16 * 32];
            alf[m] = *(const bf16x8*)&Al[abase + m * 16 * 32];
        }
#pragma unroll
        for (int n = 0; n < 2; n++) {
            bhf[n] = *(const bf16x8*)&Bh[bbase + n * 16 * 32];
            blf[n] = *(const bf16x8*)&Bl[bbase + n * 16 * 32];
        }
#pragma unroll
        for (int m = 0; m < 4; m++)
#pragma unroll
            for (int n = 0; n < 2; n++) {
                acc[m][n] = __builtin_amdgcn_mfma_f32_16x16x32_bf16(ahf[m], bhf[n], acc[m][n], 0, 0, 0);
                acc[m][n] = __builtin_amdgcn_mfma_f32_16x16x32_bf16(ahf[m], blf[n], acc[m][n], 0, 0, 0);
                acc[m][n] = __builtin_amdgcn_mfma_f32_16x16x32_bf16(alf[m], bhf[n], acc[m][n], 0, 0, 0);
            }
        __syncthreads();
    }
#pragma unroll
    for (int m = 0; m < 4; m++)
#pragma unroll
        for (int reg = 0; reg < 4; reg++) {
            int rrow = bm + wm * 64 + m * 16 + ks * 4 + reg;
#pragma unroll
            for (int n = 0; n < 2; n++) {
                int col = wn * 32 + n * 16 + fr;
                if (col < KMAX) Y[(size_t)rrow * KMAX + col] = acc[m][n][reg];
            }
        }
}

// ---------------------------------------------------------------------------
// Bound-guided top-20: rank the 12 tile-maxima desc; load a 128-col tile's
// 512 B only when its exact max exceeds the running 20th-best T. Identical
// result to a full scan (strict-> inserts; skipped tiles hold no value > T).
// Lanes 0..19 hold the running top-20 (sorted desc); 4 rows/block.
// ---------------------------------------------------------------------------
__global__ __launch_bounds__(256) void topk_kernel(const float* __restrict__ chunk,
                                                   const float* __restrict__ rtmax,
                                                   float* __restrict__ gval,
                                                   int* __restrict__ gidx, int c0) {
    const int lane = threadIdx.x & 63;
    const int row  = blockIdx.x * 4 + (threadIdx.x >> 6);
    float lv = -INFINITY; int li = -1;
    if (c0 > 0 && lane < KNN) {
        lv = gval[(size_t)row * KNN + lane];
        li = gidx[(size_t)row * KNN + lane];
    }
    float T = __shfl(lv, KNN - 1);
    // tile maxima in lanes 0..11; rank desc (ties by lower tile index)
    float tml = (lane < NTILE) ? rtmax[(size_t)row * NTILE + lane] : -INFINITY;
    int rank = 0;
#pragma unroll
    for (int j = 0; j < NTILE; j++) {
        float oj = __shfl(tml, j);
        if (lane < NTILE && (oj > tml || (oj == tml && j < lane))) rank++;
    }
    const float2* rp = (const float2*)(chunk + (size_t)row * CW);
    for (int t = 0; t < NTILE; t++) {
        int srcl = __ffsll((unsigned long long)__ballot(lane < NTILE && rank == t)) - 1;
        float tmt = __shfl(tml, srcl);
        if (tmt <= T) break;                 // desc order: rest can't beat T
        int tile = srcl;
        float2 v2 = rp[tile * 64 + lane];    // 128 cols, 2 per lane
        float mx2 = fmaxf(v2.x, v2.y);
        unsigned long long bal = __ballot(mx2 > T);
        while (bal) {
            int src = __ffsll((unsigned long long)bal) - 1;
            bal &= bal - 1;
            float c0v = __shfl(v2.x, src);
            float c1v = __shfl(v2.y, src);
#pragma unroll
            for (int e = 0; e < 2; e++) {
                float cv = e ? c1v : c0v;
                if (cv > T) {                // recheck vs risen T
                    int cc = c0 + tile * 128 + 2 * src + e;
                    float up = __shfl_up(lv, 1);
                    int  upi = __shfl_up(li, 1);
                    if (lane == 0) up = INFINITY;
                    bool keep = lv > cv;
                    float nv = keep ? lv : (up > cv ? cv : up);
                    int  ni = keep ? li : (up > cv ? cc : upi);
                    lv = nv; li = ni;
                    T = __shfl(lv, KNN - 1);
                }
            }
        }
    }
    if (lane < KNN) {
        gval[(size_t)row * KNN + lane] = lv;
        gidx[(size_t)row * KNN + lane] = li;
    }
}

// ---------------------------------------------------------------------------
// degrees + edge count; CSC offsets via single-block scan; CSC fill
// ---------------------------------------------------------------------------
__global__ void degree_kernel(const float* __restrict__ gval, const int* __restrict__ gidx,
                              int* __restrict__ indeg, int* __restrict__ ec) {
    int e = blockIdx.x * blockDim.x + threadIdx.x;   // exact N*KNN
    bool pass = gval[e] > THR;
    if (pass) atomicAdd(&indeg[gidx[e]], 1);
    unsigned long long b = __ballot(pass);
    if ((threadIdx.x & 63) == 0) atomicAdd(ec, (int)__popcll(b));
}

__global__ __launch_bounds__(1024) void scan_kernel(const int* __restrict__ indeg,
                                                    int* __restrict__ offs,
                                                    float* __restrict__ dinv) {
    __shared__ int part[1024];
    int tid = threadIdx.x;
    int d[6], loc[6], s = 0;
#pragma unroll
    for (int q = 0; q < 6; q++) { d[q] = indeg[tid * 6 + q]; loc[q] = s; s += d[q]; }
    part[tid] = s;
    __syncthreads();
    for (int off = 1; off < 1024; off <<= 1) {
        int v = (tid >= off) ? part[tid - off] : 0;
        __syncthreads();
        part[tid] += v;
        __syncthreads();
    }
    int pre = (tid > 0) ? part[tid - 1] : 0;
#pragma unroll
    for (int q = 0; q < 6; q++) {
        offs[tid * 6 + q] = pre + loc[q];
        dinv[tid * 6 + q] = 1.0f / sqrtf((float)(d[q] + 1));   // +1 self-loop (M = A_bin + I)
    }
    if (tid == 1023) offs[N_PTS] = part[1023];
}

__global__ void fill_kernel(const float* __restrict__ gval, const int* __restrict__ gidx,
                            const int* __restrict__ offs, int* __restrict__ fillc,
                            int* __restrict__ csc) {
    int e = blockIdx.x * blockDim.x + threadIdx.x;
    if (gval[e] > THR) {
        int j = gidx[e];
        int pos = offs[j] + atomicAdd(&fillc[j], 1);
        csc[pos] = e / KNN;               // source row i
    }
}

// ---------------------------------------------------------------------------
// GCN layer 1 aggregation (4-way unrolled gather) + relu + bf16 split of h
// ---------------------------------------------------------------------------
__global__ __launch_bounds__(256) void agg1_kernel(const float* __restrict__ Z,
                                                   const int* __restrict__ offs,
                                                   const int* __restrict__ csc,
                                                   const float* __restrict__ dinv,
                                                   const float* __restrict__ b1,
                                                   u16* __restrict__ hh,
                                                   u16* __restrict__ hl) {
    int j = blockIdx.x, f = threadIdx.x;
    float dj = dinv[j];
    float acc = dj * Z[(size_t)j * HID + f];
    int e = offs[j], e1 = offs[j + 1];
    for (; e + 4 <= e1; e += 4) {
        int i0 = csc[e], i1 = csc[e + 1], i2 = csc[e + 2], i3 = csc[e + 3];
        float w0 = dinv[i0], w1 = dinv[i1], w2 = dinv[i2], w3 = dinv[i3];
        float z0 = Z[(size_t)i0 * HID + f], z1 = Z[(size_t)i1 * HID + f];
        float z2 = Z[(size_t)i2 * HID + f], z3 = Z[(size_t)i3 * HID + f];
        acc = fmaf(w0, z0, acc); acc = fmaf(w1, z1, acc);
        acc = fmaf(w2, z2, acc); acc = fmaf(w3, z3, acc);
    }
    for (; e < e1; e++) {
        int i = csc[e];
        acc = fmaf(dinv[i], Z[(size_t)i * HID + f], acc);
    }
    float hv = fmaxf(acc * dj + b1[f], 0.f);
    u16 hb = f2bf(hv);
    hh[(size_t)j * HID + f] = hb;
    hl[(size_t)j * HID + f] = f2bf(hv - bf2f(hb));
}

// ---------------------------------------------------------------------------
// GCN layer 2 aggregation (4-way unrolled) + bias + row softmax -> S
// ---------------------------------------------------------------------------
__global__ __launch_bounds__(256) void agg2_softmax_kernel(const float* __restrict__ Y,
                                                           const int* __restrict__ offs,
                                                           const int* __restrict__ csc,
                                                           const float* __restrict__ dinv,
                                                           const float* __restrict__ b2,
                                                           float* __restrict__ S) {
    int c = threadIdx.x & 63;
    int j = blockIdx.x * 4 + (threadIdx.x >> 6);
    bool act = c < KMAX;
    float dj = dinv[j];
    float acc = act ? dj * Y[(size_t)j * KMAX + c] : 0.f;
    int e = offs[j], e1 = offs[j + 1];
    for (; e + 4 <= e1; e += 4) {
        int i0 = csc[e], i1 = csc[e + 1], i2 = csc[e + 2], i3 = csc[e + 3];
        float w0 = dinv[i0], w1 = dinv[i1], w2 = dinv[i2], w3 = dinv[i3];
        float y0 = act ? Y[(size_t)i0 * KMAX + c] : 0.f;
        float y1 = act ? Y[(size_t)i1 * KMAX + c] : 0.f;
        float y2 = act ? Y[(size_t)i2 * KMAX + c] : 0.f;
        float y3 = act ? Y[(size_t)i3 * KMAX + c] : 0.f;
        acc = fmaf(w0, y0, acc); acc = fmaf(w1, y1, acc);
        acc = fmaf(w2, y2, acc); acc = fmaf(w3, y3, acc);
    }
    for (; e < e1; e++) {
        int i = csc[e];
        if (act) acc = fmaf(dinv[i], Y[(size_t)i * KMAX + c], acc);
    }
    float s = act ? (acc * dj + b2[c]) : -INFINITY;
    float m = s;
#pragma unroll
    for (int msk = 1; msk < 64; msk <<= 1) m = fmaxf(m, __shfl_xor(m, msk));
    float ex = act ? expf(s - m) : 0.f;
    float tot = ex;
#pragma unroll
    for (int msk = 1; msk < 64; msk <<= 1) tot += __shfl_xor(tot, msk);
    if (act) S[(size_t)j * KMAX + c] = ex / tot;
}

// ---------------------------------------------------------------------------
// per-row sparse ops, prefetched edges, 4 rows/block (4 waves).
// ---------------------------------------------------------------------------
__global__ __launch_bounds__(256) void rowops_kernel(const float* __restrict__ S,
                                                     const int* __restrict__ gidx,
                                                     const float* __restrict__ gval,
                                                     const float* __restrict__ pos,
                                                     const float* __restrict__ p2,
                                                     float* __restrict__ AS,
                                                     float* __restrict__ lossrow) {
    const int lane = threadIdx.x & 63;
    const int i = blockIdx.x * 4 + (threadIdx.x >> 6);
    const int c = lane;
    const bool act = c < KMAX;
    int jl = 0; float vl = 0.f, d2l = 0.f;
    if (lane < KNN) {
        jl = gidx[(size_t)i * KNN + lane];
        vl = gval[(size_t)i * KNN + lane];
        float pxi = pos[2 * i], pyi = pos[2 * i + 1], p2i = p2[i];
        d2l = fmaxf(p2i + p2[jl] - 2.f * (pxi * pos[2 * jl] + pyi * pos[2 * jl + 1]), 0.f);
    }
    float asum = 0.f, wsum = 0.f;
#pragma unroll
    for (int e = 0; e < KNN; e++) {
        int j = __shfl(jl, e);
        float v = __shfl(vl, e);
        float d2 = __shfl(d2l, e);
        float sv = act ? S[(size_t)j * KMAX + c] : 0.f;
        asum = fmaf(v, sv, asum);
        if (v > THR) wsum = fmaf(d2, sv, wsum);
    }
    if (act) AS[(size_t)i * KMAX + c] = asum;
    float li = act ? S[(size_t)i * KMAX + c] * wsum : 0.f;
#pragma unroll
    for (int m = 1; m < 64; m <<= 1) li += __shfl_xor(li, m);
    if (lane == 0) lossrow[i] = li;
}

// single-block tree reduce of lossrow[6144] -> lossb[0]
__global__ __launch_bounds__(1024) void loss_reduce_kernel(const float* __restrict__ lossrow,
                                                           float* __restrict__ lossb) {
    int tid = threadIdx.x;
    float s = 0.f;
#pragma unroll
    for (int q = 0; q < 6; q++) s += lossrow[tid + 1024 * q];
#pragma unroll
    for (int m = 1; m < 64; m <<= 1) s += __shfl_xor(s, m);
    __shared__ float ws[16];
    if ((tid & 63) == 0) ws[tid >> 6] = s;
    __syncthreads();
    if (tid == 0) {
        float t = 0.f;
#pragma unroll
        for (int q = 0; q < 16; q++) t += ws[q];
        lossb[0] = t;
    }
}

// ---------------------------------------------------------------------------
// A_coarse partials: Acp[ch][50*50] = S[ch-rows]^T @ AS[ch-rows] (no atomics)
// ---------------------------------------------------------------------------
__global__ __launch_bounds__(256) void coarseA_kernel(const float* __restrict__ S,
                                                      const float* __restrict__ AS,
                                                      float* __restrict__ Acp) {
    __shared__ float Ss[CXC][50];
    __shared__ float Bs[CXC][50];
    int tid = threadIdx.x;
    int ch = blockIdx.x;
    int i0 = ch * CXC;
    for (int idx = tid; idx < CXC * 50; idx += 256) {
        int r = idx / 50, c = idx % 50;
        Ss[r][c] = S[(size_t)(i0 + r) * KMAX + c];
        Bs[r][c] = AS[(size_t)(i0 + r) * KMAX + c];
    }
    __syncthreads();
    float acc[10];
    int ca[10], cb[10];
#pragma unroll
    for (int q = 0; q < 10; q++) {
        acc[q] = 0.f;
        int cell = tid + 256 * q;
        ca[q] = cell / 50; cb[q] = cell % 50;
    }
    for (int r = 0; r < CXC; r++) {
#pragma unroll
        for (int q = 0; q < 10; q++) {
            if (tid + 256 * q < 2500)
                acc[q] = fmaf(Ss[r][ca[q]], Bs[r][cb[q]], acc[q]);
        }
    }
#pragma unroll
    for (int q = 0; q < 10; q++) {
        int cell = tid + 256 * q;
        if (cell < 2500) Acp[(size_t)ch * 2500 + cell] = acc[q];
    }
}

// ---------------------------------------------------------------------------
// X_t partials: Xtp[ch][50][512] = S[ch-rows]^T @ X[ch-rows] (no atomics)
// ---------------------------------------------------------------------------
__global__ __launch_bounds__(64) void coarseX_kernel(const float* __restrict__ S,
                                                     const float* __restrict__ X,
                                                     float* __restrict__ Xtp) {
    __shared__ float Ss[CXC][50];
    const int lane = threadIdx.x;
    const int ch = blockIdx.x >> 3;
    const int f = ((blockIdx.x & 7) << 6) + lane;
    const int i0 = ch * CXC;
    for (int idx = lane; idx < CXC * 50; idx += 64) {
        Ss[idx / 50][idx % 50] = S[(size_t)(i0 + idx / 50) * KMAX + idx % 50];
    }
    __syncthreads();
    float acc[50];
#pragma unroll
    for (int a = 0; a < 50; a++) acc[a] = 0.f;
    const float* xp = X + (size_t)i0 * FEAT + f;
#pragma unroll 4
    for (int r = 0; r < CXC; r++) {
        float xv = xp[(size_t)r * FEAT];
#pragma unroll
        for (int a = 0; a < 50; a++) acc[a] = fmaf(Ss[r][a], xv, acc[a]);
    }
#pragma unroll
    for (int a = 0; a < 50; a++)
        Xtp[((size_t)ch * KMAX + a) * FEAT + f] = acc[a];
}

// reduce X_t partials: out_Xt[cell] = sum_ch Xtp[ch][cell]
__global__ __launch_bounds__(256) void reduceX_kernel(const float* __restrict__ Xtp,
                                                      float* __restrict__ Xt) {
    int cell = blockIdx.x * 256 + threadIdx.x;
    if (cell < KMAX * FEAT) {
        float s0 = 0.f, s1 = 0.f, s2 = 0.f, s3 = 0.f;
        for (int ch = 0; ch < NCHX; ch += 4) {
            s0 += Xtp[(size_t)ch * KMAX * FEAT + cell];
            s1 += Xtp[(size_t)(ch + 1) * KMAX * FEAT + cell];
            s2 += Xtp[(size_t)(ch + 2) * KMAX * FEAT + cell];
            s3 += Xtp[(size_t)(ch + 3) * KMAX * FEAT + cell];
        }
        Xt[cell] = (s0 + s1) + (s2 + s3);
    }
}

// ---------------------------------------------------------------------------
// finalize: reduce A_coarse partials + threshold; L_spatial, lam
// ---------------------------------------------------------------------------
__global__ __launch_bounds__(256) void finalize_kernel(const float* __restrict__ Acp,
                                                       const float* __restrict__ loss,
                                                       const int* __restrict__ ec,
                                                       const float* __restrict__ sw,
                                                       const float* __restrict__ lamw,
                                                       float* __restrict__ out_At,
                                                       float* __restrict__ out_scalars) {
    int t = blockIdx.x * blockDim.x + threadIdx.x;
    if (t < KMAX * KMAX) {
        float s0 = 0.f, s1 = 0.f, s2 = 0.f, s3 = 0.f;
        for (int ch = 0; ch < NCHX; ch += 4) {
            s0 += Acp[(size_t)ch * 2500 + t];
            s1 += Acp[(size_t)(ch + 1) * 2500 + t];
            s2 += Acp[(size_t)(ch + 2) * 2500 + t];
            s3 += Acp[(size_t)(ch + 3) * 2500 + t];
        }
        float v = (s0 + s1) + (s2 + s3);
        out_At[t] = (v > THR) ? v : 0.f;
    }
    if (t == 0) {
        out_scalars[0] = sw[0] * loss[0] / (float)ec[0];     // L_spatial
        out_scalars[1] = 1.f / (1.f + expf(-lamw[0]));       // lam
    }
}

// ---------------------------------------------------------------------------
// launch
// ---------------------------------------------------------------------------
extern "C" void kernel_launch(void* const* d_in, const int* in_sizes, int n_in,
                              void* d_out, int out_size, void* d_ws, size_t ws_size,
                              hipStream_t stream) {
    const float* features = (const float*)d_in[0];
    const float* positions = (const float*)d_in[1];
    const float* lambda_w  = (const float*)d_in[2];
    const float* temp_w    = (const float*)d_in[3];
    const float* spatial_w = (const float*)d_in[4];
    const float* W1 = (const float*)d_in[5];
    const float* b1 = (const float*)d_in[6];
    const float* W2 = (const float*)d_in[7];
    const float* b2 = (const float*)d_in[8];

    float* out = (float*)d_out;
    // output layout: S [N*50] | X_t [50*512] | A_t [50*50] | L_spatial | lam
    float* out_S  = out;
    float* out_Xt = out + (size_t)N_PTS * KMAX;
    float* out_At = out_Xt + KMAX * FEAT;
    float* out_sc = out_At + KMAX * KMAX;

    // workspace layout (~67 MB total)
    char* ws = (char*)d_ws;
    size_t off = 0;
    auto alloc = [&](size_t bytes) { size_t o = off; off = (off + bytes + 255) & ~(size_t)255; return o; };
    u16*   fnh     = (u16*)  (ws + alloc((size_t)N_PTS * FEAT * 2));
    u16*   fnl     = (u16*)  (ws + alloc((size_t)N_PTS * FEAT * 2));
    u16*   fh      = (u16*)  (ws + alloc((size_t)N_PTS * FEAT * 2));
    u16*   fl      = (u16*)  (ws + alloc((size_t)N_PTS * FEAT * 2));
    float* p2      = (float*)(ws + alloc((size_t)N_PTS * 4));
    float* adjchnk = (float*)(ws + alloc((size_t)N_PTS * CW * 4));
    float* rtmax   = (float*)(ws + alloc((size_t)N_PTS * NTILE * 4));
    float* gval    = (float*)(ws + alloc((size_t)N_PTS * KNN * 4));
    int*   gidx    = (int*)  (ws + alloc((size_t)N_PTS * KNN * 4));
    int*   indeg   = (int*)  (ws + alloc((size_t)N_PTS * 4));
    int*   fillc   = (int*)  (ws + alloc((size_t)N_PTS * 4));
    int*   offs    = (int*)  (ws + alloc((size_t)(N_PTS + 1) * 4));
    float* dinv    = (float*)(ws + alloc((size_t)N_PTS * 4));
    int*   csc     = (int*)  (ws + alloc((size_t)N_PTS * KNN * 4));
    u16*   w1th    = (u16*)  (ws + alloc((size_t)HID * FEAT * 2));
    u16*   w1tl    = (u16*)  (ws + alloc((size_t)HID * FEAT * 2));
    u16*   w2th    = (u16*)  (ws + alloc((size_t)64 * HID * 2));
    u16*   w2tl    = (u16*)  (ws + alloc((size_t)64 * HID * 2));
    float* lossrow = (float*)(ws + alloc((size_t)N_PTS * 4));
    float* lossb   = (float*)(ws + alloc(4));
    int*   ecnt    = (int*)  (ws + alloc(4));

    // post-topk buffers overlaid into the dead adjchnk region (37.7 MB)
    char* ov = (char*)adjchnk;
    float* Z   = (float*)(ov);                                  // 6.29 MB
    u16*   hh  = (u16*)  (ov + 7 * 1024 * 1024);                // 3.15 MB
    u16*   hl  = (u16*)  (ov + 11 * 1024 * 1024);               // 3.15 MB
    float* Y   = (float*)(ov + 15 * 1024 * 1024);               // 1.23 MB
    float* AS  = (float*)(ov + 17 * 1024 * 1024);               // 1.23 MB
    float* Xtp = (float*)(ov + 19 * 1024 * 1024);               // 9.83 MB (96x50x512)
    float* Acp = (float*)(ov + 30 * 1024 * 1024);               // 0.96 MB (96x2500)

    // 1. init accumulators
    init_kernel<<<(N_PTS + 255) / 256, 256, 0, stream>>>(indeg, fillc, ecnt);
    // 2. normalize (emit bf16 hi/lo of fn and raw f) + p2 + weight transposes
    normalize_kernel<<<N_PTS, 64, 0, stream>>>(features, fnh, fnl, fh, fl);
    p2_kernel<<<(N_PTS + 255) / 256, 256, 0, stream>>>(positions, p2);
    w1t_split_kernel<<<HID, 256, 0, stream>>>(W1, w1th, w1tl);
    w2t_split_kernel<<<64, 256, 0, stream>>>(W2, w2th, w2tl);
    // 3. adj chunks (MFMA + rtmax side output) + bound-guided top-20 merge
    for (int c = 0; c < NCHUNK; c++) {
        gemm_adj_mfma_kernel<<<dim3(NTILE, N_PTS / 128), 512, 0, stream>>>(
            fnh, fnl, positions, p2, lambda_w, temp_w, adjchnk, rtmax, c * CW);
        topk_kernel<<<N_PTS / 4, 256, 0, stream>>>(adjchnk, rtmax, gval, gidx, c * CW);
    }
    // 4. degrees / E, CSC offsets, CSC fill
    degree_kernel<<<(N_PTS * KNN) / 256, 256, 0, stream>>>(gval, gidx, indeg, ecnt);
    scan_kernel<<<1, 1024, 0, stream>>>(indeg, offs, dinv);
    fill_kernel<<<(N_PTS * KNN) / 256, 256, 0, stream>>>(gval, gidx, offs, fillc, csc);
    // 5. GCN layer 1: Z = X@W1 (MFMA) ; h = relu(agg(Z)+b1) -> bf16 split
    gemm_z_kernel<<<dim3(HID / 128, N_PTS / 128), 256, 0, stream>>>(fh, fl, w1th, w1tl, Z);
    agg1_kernel<<<N_PTS, HID, 0, stream>>>(Z, offs, csc, dinv, b1, hh, hl);
    // 6. GCN layer 2: Y = h@W2 (MFMA) ; s = agg(Y)+b2 ; S = softmax(s)
    gemm_y_kernel<<<N_PTS / 128, 256, 0, stream>>>(hh, hl, w2th, w2tl, Y);
    agg2_softmax_kernel<<<N_PTS / 4, 256, 0, stream>>>(Y, offs, csc, dinv, b2, out_S);
    // 7. AS = adj@S, per-row loss, loss reduce
    rowops_kernel<<<N_PTS / 4, 256, 0, stream>>>(out_S, gidx, gval, positions, p2, AS, lossrow);
    loss_reduce_kernel<<<1, 1024, 0, stream>>>(lossrow, lossb);
    // 8. coarsening via split-K partials (no atomics) + reduces
    coarseA_kernel<<<NCHX, 256, 0, stream>>>(out_S, AS, Acp);
    coarseX_kernel<<<NCHX * 8, 64, 0, stream>>>(out_S, features, Xtp);
    reduceX_kernel<<<(KMAX * FEAT + 255) / 256, 256, 0, stream>>>(Xtp, out_Xt);
    // 9. finalize: A_t reduce+threshold, scalars
    finalize_kernel<<<(KMAX * KMAX + 255) / 256, 256, 0, stream>>>(Acp, lossb, ecnt, spatial_w, lambda_w, out_At, out_sc);
}

// Round 12
// 487.061 us; speedup vs baseline: 1.0273x; 1.0273x over previous
//
#include <hip/hip_runtime.h>
#include <hip/hip_bf16.h>
#include <math.h>

// Problem constants
#define N_PTS   6144
#define FEAT    512
#define HID     256
#define KMAX    50
#define KNN     20
#define THR     0.1f
#define CW      1536        // adj column-chunk width (4 chunks of 1536)
#define NCHUNK  4
#define CXC     64          // coarsening rows per chunk
#define NCHX    (N_PTS / CXC)   // 96 partial chunks

typedef unsigned short u16;
typedef __attribute__((ext_vector_type(8))) short bf16x8;
typedef __attribute__((ext_vector_type(8))) u16   u16x8;
typedef __attribute__((ext_vector_type(4))) float f32x4;

// round-to-nearest-even fp32 -> bf16 (inputs finite)
__device__ __forceinline__ u16 f2bf(float x) {
    union { float f; unsigned u; } a; a.f = x;
    unsigned r = (a.u + 0x7fffu + ((a.u >> 16) & 1u)) >> 16;
    return (u16)r;
}
__device__ __forceinline__ float bf2f(u16 h) {
    union { unsigned u; float f; } a; a.u = ((unsigned)h) << 16;
    return a.f;
}

__device__ __forceinline__ void gload16(const void* g, void* l) {
    __builtin_amdgcn_global_load_lds(
        (const __attribute__((address_space(1))) void*)g,
        (__attribute__((address_space(3))) void*)l, 16, 0, 0);
}

// ---------------------------------------------------------------------------
// init: zero accumulators (ws/d_out are poisoned 0xAA before every launch)
// ---------------------------------------------------------------------------
__global__ void init_kernel(int* __restrict__ indeg, int* __restrict__ fillc,
                            int* __restrict__ ec) {
    int t = blockIdx.x * blockDim.x + threadIdx.x;
    if (t < N_PTS) { indeg[t] = 0; fillc[t] = 0; }
    if (t == 0) { ec[0] = 0; }
}

// ---------------------------------------------------------------------------
// fn = features/||row||; emit bf16 hi/lo of normalized AND raw features
// ---------------------------------------------------------------------------
__global__ __launch_bounds__(64) void normalize_kernel(const float* __restrict__ f,
                                                       u16* __restrict__ fnh,
                                                       u16* __restrict__ fnl,
                                                       u16* __restrict__ fh_,
                                                       u16* __restrict__ fl_) {
    int row = blockIdx.x, lane = threadIdx.x;
    const float4* fr = (const float4*)(f + (size_t)row * FEAT);
    float4 v0 = fr[lane * 2 + 0];
    float4 v1 = fr[lane * 2 + 1];
    float ss = v0.x * v0.x + v0.y * v0.y + v0.z * v0.z + v0.w * v0.w
             + v1.x * v1.x + v1.y * v1.y + v1.z * v1.z + v1.w * v1.w;
#pragma unroll
    for (int m = 1; m < 64; m <<= 1) ss += __shfl_xor(ss, m);
    float nrm = fmaxf(sqrtf(ss), 1e-12f);
    float r[8] = { v0.x, v0.y, v0.z, v0.w, v1.x, v1.y, v1.z, v1.w };
    u16x8 h, l, rh, rl;
#pragma unroll
    for (int q = 0; q < 8; q++) {
        float vn = r[q] / nrm;
        u16 hb = f2bf(vn);
        h[q] = hb; l[q] = f2bf(vn - bf2f(hb));
        u16 rb = f2bf(r[q]);
        rh[q] = rb; rl[q] = f2bf(r[q] - bf2f(rb));
    }
    size_t base = (size_t)row * FEAT + lane * 8;
    *(u16x8*)(fnh + base) = h;
    *(u16x8*)(fnl + base) = l;
    *(u16x8*)(fh_ + base) = rh;
    *(u16x8*)(fl_ + base) = rl;
}

// p2[i] = x^2 + y^2
__global__ void p2_kernel(const float* __restrict__ pos, float* __restrict__ p2) {
    int i = blockIdx.x * blockDim.x + threadIdx.x;
    if (i < N_PTS) {
        float x = pos[2 * i], y = pos[2 * i + 1];
        p2[i] = x * x + y * y;
    }
}

// transpose + split W1 [512][256] -> W1T hi/lo [256][512]
__global__ __launch_bounds__(256) void w1t_split_kernel(const float* __restrict__ W1,
                                                        u16* __restrict__ th,
                                                        u16* __restrict__ tl) {
    int n = blockIdx.x;
    for (int k = threadIdx.x; k < FEAT; k += 256) {
        float v = W1[(size_t)k * HID + n];
        u16 hb = f2bf(v);
        th[(size_t)n * FEAT + k] = hb;
        tl[(size_t)n * FEAT + k] = f2bf(v - bf2f(hb));
    }
}

// transpose + split W2 [256][50] -> W2T hi/lo [64][256] (rows 50..63 zero)
__global__ __launch_bounds__(256) void w2t_split_kernel(const float* __restrict__ W2,
                                                        u16* __restrict__ th,
                                                        u16* __restrict__ tl) {
    int n = blockIdx.x, k = threadIdx.x;
    float v = (n < KMAX) ? W2[(size_t)k * KMAX + n] : 0.f;
    u16 hb = f2bf(v);
    th[(size_t)n * HID + k] = hb;
    tl[(size_t)n * HID + k] = f2bf(v - bf2f(hb));
}

// ---------------------------------------------------------------------------
// LDS swizzle scheme (verified R6: conflicts 2.36M -> 0):
//   LDS tile [R][32]u16, 64B rows of four 16B slots. slot' = slot ^ ((row>>1)&3).
//   Stage keeps LDS dest LINEAR (global_load_lds) and pre-swizzles the GLOBAL
//   source k-slot; ds_read applies the same XOR.
// ---------------------------------------------------------------------------

// ---------------------------------------------------------------------------
// adj chunk via MFMA bf16 hi/lo split, 8 waves/block (R10 version):
//   sim = Ah.Bh^T + Ah.Bl^T + Al.Bh^T; fused sigmoid/spatial epilogue.
// 128x128 tile, BK=32, wave grid 2x4 (each wave 64 rows x 32 cols).
// ---------------------------------------------------------------------------
__global__ __launch_bounds__(512) void gemm_adj_mfma_kernel(
    const u16* __restrict__ fnh, const u16* __restrict__ fnl,
    const float* __restrict__ pos, const float* __restrict__ p2,
    const float* __restrict__ lamw, const float* __restrict__ tempw,
    float* __restrict__ out, int c0) {
    __shared__ u16 Ah[128 * 32], Al[128 * 32], Bh[128 * 32], Bl[128 * 32];
    const int tid  = threadIdx.x;
    const int lane = tid & 63, wid = tid >> 6;
    const int wm = wid >> 2, wn = wid & 3;       // 2x4 wave grid
    // XCD-aware bijective remap: 576 blocks, 72 contiguous per XCD
    const int flat = blockIdx.y * gridDim.x + blockIdx.x;
    const int nwg  = gridDim.x * gridDim.y;
    const int swzb = (flat & 7) * (nwg >> 3) + (flat >> 3);
    const int bx = swzb % gridDim.x, by = swzb / gridDim.x;
    const int bm  = by * 128;                    // global row base
    const int bnl = bx * 128;                    // chunk-local col base
    const int bng = c0 + bnl;                    // global col base

    // staging: wave w covers half (w&1) of buffer (w>>1); 4 issues x 16 rows
    const int sbuf = wid >> 1, shalf = wid & 1;
    const u16* src = (sbuf & 1) ? fnl : fnh;
    u16* dst = (sbuf == 0) ? Ah : (sbuf == 1) ? Al : (sbuf == 2) ? Bh : Bl;
    const int grow = (sbuf >> 1) ? bng : bm;
    const u16* gbase = src + (size_t)(grow + shalf * 64 + (lane >> 2)) * FEAT
                     + (((lane & 3) ^ ((lane >> 3) & 3)) * 8);
    u16* ldst = dst + (shalf * 64) * 32;

    f32x4 acc[4][2];
#pragma unroll
    for (int m = 0; m < 4; m++)
#pragma unroll
        for (int n = 0; n < 2; n++) acc[m][n] = (f32x4){0.f, 0.f, 0.f, 0.f};

    const int fr = lane & 15;     // fragment row/col
    const int ks = lane >> 4;     // k-slot (8 bf16 each)
    const int ksw = (ks ^ ((fr >> 1) & 3)) * 8;  // swizzled slot offset
    const int abase = (wm * 64 + fr) * 32 + ksw;
    const int bbase = (wn * 32 + fr) * 32 + ksw;

    for (int k0 = 0; k0 < FEAT; k0 += 32) {
#pragma unroll
        for (int i = 0; i < 4; i++)
            gload16(gbase + k0 + (size_t)i * 16 * FEAT, ldst + i * 512);
        __syncthreads();
        bf16x8 ahf[4], alf[4], bhf[2], blf[2];
#pragma unroll
        for (int m = 0; m < 4; m++) {
            ahf[m] = *(const bf16x8*)&Ah[abase + m * 16 * 32];
            alf[m] = *(const bf16x8*)&Al[abase + m * 16 * 32];
        }
#pragma unroll
        for (int n = 0; n < 2; n++) {
            bhf[n] = *(const bf16x8*)&Bh[bbase + n * 16 * 32];
            blf[n] = *(const bf16x8*)&Bl[bbase + n * 16 * 32];
        }
#pragma unroll
        for (int m = 0; m < 4; m++)
#pragma unroll
            for (int n = 0; n < 2; n++) {
                acc[m][n] = __builtin_amdgcn_mfma_f32_16x16x32_bf16(ahf[m], bhf[n], acc[m][n], 0, 0, 0);
                acc[m][n] = __builtin_amdgcn_mfma_f32_16x16x32_bf16(ahf[m], blf[n], acc[m][n], 0, 0, 0);
                acc[m][n] = __builtin_amdgcn_mfma_f32_16x16x32_bf16(alf[m], bhf[n], acc[m][n], 0, 0, 0);
            }
        __syncthreads();
    }

    // epilogue: fuse spatial kernel + sigmoid.
    // C/D layout (16x16x32): col = lane&15, row = (lane>>4)*4 + reg
    float lam  = 1.f / (1.f + __expf(-lamw[0]));
    float temp = tempw[0];
    float p2c[2], pxc[2], pyc[2];
#pragma unroll
    for (int n = 0; n < 2; n++) {
        int cg = bng + wn * 32 + n * 16 + fr;
        p2c[n] = p2[cg]; pxc[n] = pos[2 * cg]; pyc[n] = pos[2 * cg + 1];
    }
#pragma unroll
    for (int m = 0; m < 4; m++) {
#pragma unroll
        for (int reg = 0; reg < 4; reg++) {
            int rrow = bm + wm * 64 + m * 16 + ks * 4 + reg;
            float p2r = p2[rrow], pxr = pos[2 * rrow], pyr = pos[2 * rrow + 1];
#pragma unroll
            for (int n = 0; n < 2; n++) {
                float sim = acc[m][n][reg];
                float d2 = fmaxf(p2r + p2c[n] - 2.f * (pxr * pxc[n] + pyr * pyc[n]), 0.f);
                float sk = __expf(-d2 * (1.f / 5000.f));
                float arg = (lam * sim + (1.f - lam) * sk) * temp;
                out[(size_t)rrow * CW + bnl + wn * 32 + n * 16 + fr] = 1.f / (1.f + __expf(-arg));
            }
        }
    }
}

// ---------------------------------------------------------------------------
// Z = X @ W1 via MFMA hi/lo split. 128x128 tile, K=512. B = W1T [256][512].
// ---------------------------------------------------------------------------
__global__ __launch_bounds__(256) void gemm_z_kernel(
    const u16* __restrict__ xh, const u16* __restrict__ xl,
    const u16* __restrict__ w1th, const u16* __restrict__ w1tl,
    float* __restrict__ Z) {
    __shared__ u16 Ah[128 * 32], Al[128 * 32], Bh[128 * 32], Bl[128 * 32];
    const int tid  = threadIdx.x;
    const int lane = tid & 63, wid = tid >> 6;
    const int wm = wid >> 1, wn = wid & 1;
    const int flat = blockIdx.y * gridDim.x + blockIdx.x;
    const int nwg  = gridDim.x * gridDim.y;
    const int swzb = (flat & 7) * (nwg >> 3) + (flat >> 3);
    const int bm = (swzb / gridDim.x) * 128;
    const int bn = (swzb % gridDim.x) * 128;

    const u16* src; u16* dst; int grow;
    if      (wid == 0) { src = xh;   dst = Ah; grow = bm; }
    else if (wid == 1) { src = xl;   dst = Al; grow = bm; }
    else if (wid == 2) { src = w1th; dst = Bh; grow = bn; }
    else               { src = w1tl; dst = Bl; grow = bn; }
    const u16* gbase = src + (size_t)(grow + (lane >> 2)) * FEAT
                     + (((lane & 3) ^ ((lane >> 3) & 3)) * 8);

    f32x4 acc[4][4];
#pragma unroll
    for (int m = 0; m < 4; m++)
#pragma unroll
        for (int n = 0; n < 4; n++) acc[m][n] = (f32x4){0.f, 0.f, 0.f, 0.f};

    const int fr = lane & 15;
    const int ks = lane >> 4;
    const int ksw = (ks ^ ((fr >> 1) & 3)) * 8;
    const int abase = (wm * 64 + fr) * 32 + ksw;
    const int bbase = (wn * 64 + fr) * 32 + ksw;

    for (int k0 = 0; k0 < FEAT; k0 += 32) {
#pragma unroll
        for (int i = 0; i < 8; i++)
            gload16(gbase + k0 + (size_t)i * 16 * FEAT, dst + i * 512);
        __syncthreads();
        bf16x8 ahf[4], alf[4], bhf[4], blf[4];
#pragma unroll
        for (int m = 0; m < 4; m++) {
            ahf[m] = *(const bf16x8*)&Ah[abase + m * 16 * 32];
            alf[m] = *(const bf16x8*)&Al[abase + m * 16 * 32];
        }
#pragma unroll
        for (int n = 0; n < 4; n++) {
            bhf[n] = *(const bf16x8*)&Bh[bbase + n * 16 * 32];
            blf[n] = *(const bf16x8*)&Bl[bbase + n * 16 * 32];
        }
#pragma unroll
        for (int m = 0; m < 4; m++)
#pragma unroll
            for (int n = 0; n < 4; n++) {
                acc[m][n] = __builtin_amdgcn_mfma_f32_16x16x32_bf16(ahf[m], bhf[n], acc[m][n], 0, 0, 0);
                acc[m][n] = __builtin_amdgcn_mfma_f32_16x16x32_bf16(ahf[m], blf[n], acc[m][n], 0, 0, 0);
                acc[m][n] = __builtin_amdgcn_mfma_f32_16x16x32_bf16(alf[m], bhf[n], acc[m][n], 0, 0, 0);
            }
        __syncthreads();
    }
#pragma unroll
    for (int m = 0; m < 4; m++)
#pragma unroll
        for (int reg = 0; reg < 4; reg++) {
            int rrow = bm + wm * 64 + m * 16 + ks * 4 + reg;
#pragma unroll
            for (int n = 0; n < 4; n++)
                Z[(size_t)rrow * HID + bn + wn * 64 + n * 16 + fr] = acc[m][n][reg];
        }
}

// ---------------------------------------------------------------------------
// Y = h @ W2 via MFMA hi/lo split. 128x64 tile, K=256. B = W2T [64][256].
// ---------------------------------------------------------------------------
__global__ __launch_bounds__(256) void gemm_y_kernel(
    const u16* __restrict__ hh, const u16* __restrict__ hl,
    const u16* __restrict__ w2th, const u16* __restrict__ w2tl,
    float* __restrict__ Y) {
    __shared__ u16 Ah[128 * 32], Al[128 * 32], Bh[64 * 32], Bl[64 * 32];
    const int tid  = threadIdx.x;
    const int lane = tid & 63, wid = tid >> 6;
    const int wm = wid >> 1, wn = wid & 1;       // wave: 64 rows x 32 cols
    const int bm = blockIdx.x * 128;

    const u16* src; u16* dst; int grow; int nld;
    if      (wid == 0) { src = hh;   dst = Ah; grow = bm; nld = 8; }
    else if (wid == 1) { src = hl;   dst = Al; grow = bm; nld = 8; }
    else if (wid == 2) { src = w2th; dst = Bh; grow = 0;  nld = 4; }
    else               { src = w2tl; dst = Bl; grow = 0;  nld = 4; }
    const u16* gbase = src + (size_t)(grow + (lane >> 2)) * HID
                     + (((lane & 3) ^ ((lane >> 3) & 3)) * 8);

    f32x4 acc[4][2];
#pragma unroll
    for (int m = 0; m < 4; m++)
#pragma unroll
        for (int n = 0; n < 2; n++) acc[m][n] = (f32x4){0.f, 0.f, 0.f, 0.f};

    const int fr = lane & 15;
    const int ks = lane >> 4;
    const int ksw = (ks ^ ((fr >> 1) & 3)) * 8;
    const int abase = (wm * 64 + fr) * 32 + ksw;
    const int bbase = (wn * 32 + fr) * 32 + ksw;

    for (int k0 = 0; k0 < HID; k0 += 32) {
        for (int i = 0; i < nld; i++)
            gload16(gbase + k0 + (size_t)i * 16 * HID, dst + i * 512);
        __syncthreads();
        bf16x8 ahf[4], alf[4], bhf[2], blf[2];
#pragma unroll
        for (int m = 0; m < 4; m++) {
            ahf[m] = *(const bf16x8*)&Ah[abase + m * 16 * 32];
            alf[m] = *(const bf16x8*)&Al[abase + m * 16 * 32];
        }
#pragma unroll
        for (int n = 0; n < 2; n++) {
            bhf[n] = *(const bf16x8*)&Bh[bbase + n * 16 * 32];
            blf[n] = *(const bf16x8*)&Bl[bbase + n * 16 * 32];
        }
#pragma unroll
        for (int m = 0; m < 4; m++)
#pragma unroll
            for (int n = 0; n < 2; n++) {
                acc[m][n] = __builtin_amdgcn_mfma_f32_16x16x32_bf16(ahf[m], bhf[n], acc[m][n], 0, 0, 0);
                acc[m][n] = __builtin_amdgcn_mfma_f32_16x16x32_bf16(ahf[m], blf[n], acc[m][n], 0, 0, 0);
                acc[m][n] = __builtin_amdgcn_mfma_f32_16x16x32_bf16(alf[m], bhf[n], acc[m][n], 0, 0, 0);
            }
        __syncthreads();
    }
#pragma unroll
    for (int m = 0; m < 4; m++)
#pragma unroll
        for (int reg = 0; reg < 4; reg++) {
            int rrow = bm + wm * 64 + m * 16 + ks * 4 + reg;
#pragma unroll
            for (int n = 0; n < 2; n++) {
                int col = wn * 32 + n * 16 + fr;
                if (col < KMAX) Y[(size_t)rrow * KMAX + col] = acc[m][n][reg];
            }
        }
}

// ---------------------------------------------------------------------------
// top-20 per row via wave-distributed sorted list + ballot-gated insert.
// R12: row staged through LDS with global_load_lds (6 wave-level 1KB DMA
// issues, all in flight; no VGPR-pressure load sinking possible). Insert
// logic identical to R10 (verified). 4 rows/block, 1 wave per row.
// ---------------------------------------------------------------------------
__global__ __launch_bounds__(256) void topk_kernel(const float* __restrict__ chunk,
                                                   float* __restrict__ gval,
                                                   int* __restrict__ gidx, int c0) {
    __shared__ float srow[4][CW];
    const int lane = threadIdx.x & 63;
    const int wid  = threadIdx.x >> 6;
    const int row  = blockIdx.x * 4 + wid;
    // stage this wave's row: 6 x 1KB DMA, per-lane global src, uniform LDS base
    const float* rp = chunk + (size_t)row * CW;
#pragma unroll
    for (int i = 0; i < CW / 256; i++)
        gload16(rp + i * 256 + lane * 4, &srow[wid][i * 256]);

    float lv = -INFINITY; int li = -1;
    if (c0 > 0 && lane < KNN) {
        lv = gval[(size_t)row * KNN + lane];
        li = gidx[(size_t)row * KNN + lane];
    }
    float T = __shfl(lv, KNN - 1);
    __syncthreads();    // drains vmcnt(0): all staged rows resident

    const float4* lp = (const float4*)srow[wid];
    float4 q[CW / 256];
#pragma unroll
    for (int b = 0; b < CW / 256; b++) q[b] = lp[lane + 64 * b];
    float m[CW / 256];
#pragma unroll
    for (int b = 0; b < CW / 256; b++)
        m[b] = fmaxf(fmaxf(q[b].x, q[b].y), fmaxf(q[b].z, q[b].w));
    float gm = m[0];
#pragma unroll
    for (int b = 1; b < CW / 256; b++) gm = fmaxf(gm, m[b]);
#pragma unroll
    for (int msk = 1; msk < 64; msk <<= 1) gm = fmaxf(gm, __shfl_xor(gm, msk));

    if (gm > T) {
#pragma unroll
        for (int b = 0; b < CW / 256; b++) {
            unsigned long long bb = __ballot(m[b] > T);
            if (!bb) continue;                       // batch can't contribute
            float vv[4] = { q[b].x, q[b].y, q[b].z, q[b].w };
#pragma unroll
            for (int e = 0; e < 4; e++) {
                unsigned long long bal = __ballot(vv[e] > T);
                while (bal) {
                    int src = __ffsll((unsigned long long)bal) - 1;
                    bal &= bal - 1;
                    float cv = __shfl(vv[e], src);
                    if (cv > T) {                    // recheck vs risen T
                        int cc = c0 + 4 * (src + 64 * b) + e;
                        float up = __shfl_up(lv, 1);
                        int  upi = __shfl_up(li, 1);
                        if (lane == 0) up = INFINITY;
                        bool keep = lv > cv;
                        float nv = keep ? lv : (up > cv ? cv : up);
                        int  ni = keep ? li : (up > cv ? cc : upi);
                        lv = nv; li = ni;
                        T = __shfl(lv, KNN - 1);
                    }
                }
            }
        }
    }
    if (lane < KNN) {
        gval[(size_t)row * KNN + lane] = lv;
        gidx[(size_t)row * KNN + lane] = li;
    }
}

// ---------------------------------------------------------------------------
// degrees + edge count; CSC offsets via single-block scan; CSC fill
// ---------------------------------------------------------------------------
__global__ void degree_kernel(const float* __restrict__ gval, const int* __restrict__ gidx,
                              int* __restrict__ indeg, int* __restrict__ ec) {
    int e = blockIdx.x * blockDim.x + threadIdx.x;   // exact N*KNN
    bool pass = gval[e] > THR;
    if (pass) atomicAdd(&indeg[gidx[e]], 1);
    unsigned long long b = __ballot(pass);
    if ((threadIdx.x & 63) == 0) atomicAdd(ec, (int)__popcll(b));
}

__global__ __launch_bounds__(1024) void scan_kernel(const int* __restrict__ indeg,
                                                    int* __restrict__ offs,
                                                    float* __restrict__ dinv) {
    __shared__ int part[1024];
    int tid = threadIdx.x;
    int d[6], loc[6], s = 0;
#pragma unroll
    for (int q = 0; q < 6; q++) { d[q] = indeg[tid * 6 + q]; loc[q] = s; s += d[q]; }
    part[tid] = s;
    __syncthreads();
    for (int off = 1; off < 1024; off <<= 1) {
        int v = (tid >= off) ? part[tid - off] : 0;
        __syncthreads();
        part[tid] += v;
        __syncthreads();
    }
    int pre = (tid > 0) ? part[tid - 1] : 0;
#pragma unroll
    for (int q = 0; q < 6; q++) {
        offs[tid * 6 + q] = pre + loc[q];
        dinv[tid * 6 + q] = 1.0f / sqrtf((float)(d[q] + 1));   // +1 self-loop (M = A_bin + I)
    }
    if (tid == 1023) offs[N_PTS] = part[1023];
}

__global__ void fill_kernel(const float* __restrict__ gval, const int* __restrict__ gidx,
                            const int* __restrict__ offs, int* __restrict__ fillc,
                            int* __restrict__ csc) {
    int e = blockIdx.x * blockDim.x + threadIdx.x;
    if (gval[e] > THR) {
        int j = gidx[e];
        int pos = offs[j] + atomicAdd(&fillc[j], 1);
        csc[pos] = e / KNN;               // source row i
    }
}

// ---------------------------------------------------------------------------
// GCN layer 1 aggregation (4-way unrolled gather) + relu + bf16 split of h
// ---------------------------------------------------------------------------
__global__ __launch_bounds__(256) void agg1_kernel(const float* __restrict__ Z,
                                                   const int* __restrict__ offs,
                                                   const int* __restrict__ csc,
                                                   const float* __restrict__ dinv,
                                                   const float* __restrict__ b1,
                                                   u16* __restrict__ hh,
                                                   u16* __restrict__ hl) {
    int j = blockIdx.x, f = threadIdx.x;
    float dj = dinv[j];
    float acc = dj * Z[(size_t)j * HID + f];
    int e = offs[j], e1 = offs[j + 1];
    for (; e + 4 <= e1; e += 4) {
        int i0 = csc[e], i1 = csc[e + 1], i2 = csc[e + 2], i3 = csc[e + 3];
        float w0 = dinv[i0], w1 = dinv[i1], w2 = dinv[i2], w3 = dinv[i3];
        float z0 = Z[(size_t)i0 * HID + f], z1 = Z[(size_t)i1 * HID + f];
        float z2 = Z[(size_t)i2 * HID + f], z3 = Z[(size_t)i3 * HID + f];
        acc = fmaf(w0, z0, acc); acc = fmaf(w1, z1, acc);
        acc = fmaf(w2, z2, acc); acc = fmaf(w3, z3, acc);
    }
    for (; e < e1; e++) {
        int i = csc[e];
        acc = fmaf(dinv[i], Z[(size_t)i * HID + f], acc);
    }
    float hv = fmaxf(acc * dj + b1[f], 0.f);
    u16 hb = f2bf(hv);
    hh[(size_t)j * HID + f] = hb;
    hl[(size_t)j * HID + f] = f2bf(hv - bf2f(hb));
}

// ---------------------------------------------------------------------------
// GCN layer 2 aggregation (4-way unrolled) + bias + row softmax -> S
// ---------------------------------------------------------------------------
__global__ __launch_bounds__(256) void agg2_softmax_kernel(const float* __restrict__ Y,
                                                           const int* __restrict__ offs,
                                                           const int* __restrict__ csc,
                                                           const float* __restrict__ dinv,
                                                           const float* __restrict__ b2,
                                                           float* __restrict__ S) {
    int c = threadIdx.x & 63;
    int j = blockIdx.x * 4 + (threadIdx.x >> 6);
    bool act = c < KMAX;
    float dj = dinv[j];
    float acc = act ? dj * Y[(size_t)j * KMAX + c] : 0.f;
    int e = offs[j], e1 = offs[j + 1];
    for (; e + 4 <= e1; e += 4) {
        int i0 = csc[e], i1 = csc[e + 1], i2 = csc[e + 2], i3 = csc[e + 3];
        float w0 = dinv[i0], w1 = dinv[i1], w2 = dinv[i2], w3 = dinv[i3];
        float y0 = act ? Y[(size_t)i0 * KMAX + c] : 0.f;
        float y1 = act ? Y[(size_t)i1 * KMAX + c] : 0.f;
        float y2 = act ? Y[(size_t)i2 * KMAX + c] : 0.f;
        float y3 = act ? Y[(size_t)i3 * KMAX + c] : 0.f;
        acc = fmaf(w0, y0, acc); acc = fmaf(w1, y1, acc);
        acc = fmaf(w2, y2, acc); acc = fmaf(w3, y3, acc);
    }
    for (; e < e1; e++) {
        int i = csc[e];
        if (act) acc = fmaf(dinv[i], Y[(size_t)i * KMAX + c], acc);
    }
    float s = act ? (acc * dj + b2[c]) : -INFINITY;
    float m = s;
#pragma unroll
    for (int msk = 1; msk < 64; msk <<= 1) m = fmaxf(m, __shfl_xor(m, msk));
    float ex = act ? expf(s - m) : 0.f;
    float tot = ex;
#pragma unroll
    for (int msk = 1; msk < 64; msk <<= 1) tot += __shfl_xor(tot, msk);
    if (act) S[(size_t)j * KMAX + c] = ex / tot;
}

// ---------------------------------------------------------------------------
// per-row sparse ops, prefetched edges, 4 rows/block (4 waves).
// ---------------------------------------------------------------------------
__global__ __launch_bounds__(256) void rowops_kernel(const float* __restrict__ S,
                                                     const int* __restrict__ gidx,
                                                     const float* __restrict__ gval,
                                                     const float* __restrict__ pos,
                                                     const float* __restrict__ p2,
                                                     float* __restrict__ AS,
                                                     float* __restrict__ lossrow) {
    const int lane = threadIdx.x & 63;
    const int i = blockIdx.x * 4 + (threadIdx.x >> 6);
    const int c = lane;
    const bool act = c < KMAX;
    int jl = 0; float vl = 0.f, d2l = 0.f;
    if (lane < KNN) {
        jl = gidx[(size_t)i * KNN + lane];
        vl = gval[(size_t)i * KNN + lane];
        float pxi = pos[2 * i], pyi = pos[2 * i + 1], p2i = p2[i];
        d2l = fmaxf(p2i + p2[jl] - 2.f * (pxi * pos[2 * jl] + pyi * pos[2 * jl + 1]), 0.f);
    }
    float asum = 0.f, wsum = 0.f;
#pragma unroll
    for (int e = 0; e < KNN; e++) {
        int j = __shfl(jl, e);
        float v = __shfl(vl, e);
        float d2 = __shfl(d2l, e);
        float sv = act ? S[(size_t)j * KMAX + c] : 0.f;
        asum = fmaf(v, sv, asum);
        if (v > THR) wsum = fmaf(d2, sv, wsum);
    }
    if (act) AS[(size_t)i * KMAX + c] = asum;
    float li = act ? S[(size_t)i * KMAX + c] * wsum : 0.f;
#pragma unroll
    for (int m = 1; m < 64; m <<= 1) li += __shfl_xor(li, m);
    if (lane == 0) lossrow[i] = li;
}

// single-block tree reduce of lossrow[6144] -> lossb[0]
__global__ __launch_bounds__(1024) void loss_reduce_kernel(const float* __restrict__ lossrow,
                                                           float* __restrict__ lossb) {
    int tid = threadIdx.x;
    float s = 0.f;
#pragma unroll
    for (int q = 0; q < 6; q++) s += lossrow[tid + 1024 * q];
#pragma unroll
    for (int m = 1; m < 64; m <<= 1) s += __shfl_xor(s, m);
    __shared__ float ws[16];
    if ((tid & 63) == 0) ws[tid >> 6] = s;
    __syncthreads();
    if (tid == 0) {
        float t = 0.f;
#pragma unroll
        for (int q = 0; q < 16; q++) t += ws[q];
        lossb[0] = t;
    }
}

// ---------------------------------------------------------------------------
// A_coarse partials: Acp[ch][50*50] = S[ch-rows]^T @ AS[ch-rows] (no atomics)
// ---------------------------------------------------------------------------
__global__ __launch_bounds__(256) void coarseA_kernel(const float* __restrict__ S,
                                                      const float* __restrict__ AS,
                                                      float* __restrict__ Acp) {
    __shared__ float Ss[CXC][50];
    __shared__ float Bs[CXC][50];
    int tid = threadIdx.x;
    int ch = blockIdx.x;
    int i0 = ch * CXC;
    for (int idx = tid; idx < CXC * 50; idx += 256) {
        int r = idx / 50, c = idx % 50;
        Ss[r][c] = S[(size_t)(i0 + r) * KMAX + c];
        Bs[r][c] = AS[(size_t)(i0 + r) * KMAX + c];
    }
    __syncthreads();
    float acc[10];
    int ca[10], cb[10];
#pragma unroll
    for (int q = 0; q < 10; q++) {
        acc[q] = 0.f;
        int cell = tid + 256 * q;
        ca[q] = cell / 50; cb[q] = cell % 50;
    }
    for (int r = 0; r < CXC; r++) {
#pragma unroll
        for (int q = 0; q < 10; q++) {
            if (tid + 256 * q < 2500)
                acc[q] = fmaf(Ss[r][ca[q]], Bs[r][cb[q]], acc[q]);
        }
    }
#pragma unroll
    for (int q = 0; q < 10; q++) {
        int cell = tid + 256 * q;
        if (cell < 2500) Acp[(size_t)ch * 2500 + cell] = acc[q];
    }
}

// ---------------------------------------------------------------------------
// X_t partials: Xtp[ch][50][512] = S[ch-rows]^T @ X[ch-rows] (no atomics)
// ---------------------------------------------------------------------------
__global__ __launch_bounds__(64) void coarseX_kernel(const float* __restrict__ S,
                                                     const float* __restrict__ X,
                                                     float* __restrict__ Xtp) {
    __shared__ float Ss[CXC][50];
    const int lane = threadIdx.x;
    const int ch = blockIdx.x >> 3;
    const int f = ((blockIdx.x & 7) << 6) + lane;
    const int i0 = ch * CXC;
    for (int idx = lane; idx < CXC * 50; idx += 64) {
        Ss[idx / 50][idx % 50] = S[(size_t)(i0 + idx / 50) * KMAX + idx % 50];
    }
    __syncthreads();
    float acc[50];
#pragma unroll
    for (int a = 0; a < 50; a++) acc[a] = 0.f;
    const float* xp = X + (size_t)i0 * FEAT + f;
#pragma unroll 4
    for (int r = 0; r < CXC; r++) {
        float xv = xp[(size_t)r * FEAT];
#pragma unroll
        for (int a = 0; a < 50; a++) acc[a] = fmaf(Ss[r][a], xv, acc[a]);
    }
#pragma unroll
    for (int a = 0; a < 50; a++)
        Xtp[((size_t)ch * KMAX + a) * FEAT + f] = acc[a];
}

// reduce X_t partials: out_Xt[cell] = sum_ch Xtp[ch][cell]
__global__ __launch_bounds__(256) void reduceX_kernel(const float* __restrict__ Xtp,
                                                      float* __restrict__ Xt) {
    int cell = blockIdx.x * 256 + threadIdx.x;
    if (cell < KMAX * FEAT) {
        float s0 = 0.f, s1 = 0.f, s2 = 0.f, s3 = 0.f;
        for (int ch = 0; ch < NCHX; ch += 4) {
            s0 += Xtp[(size_t)ch * KMAX * FEAT + cell];
            s1 += Xtp[(size_t)(ch + 1) * KMAX * FEAT + cell];
            s2 += Xtp[(size_t)(ch + 2) * KMAX * FEAT + cell];
            s3 += Xtp[(size_t)(ch + 3) * KMAX * FEAT + cell];
        }
        Xt[cell] = (s0 + s1) + (s2 + s3);
    }
}

// ---------------------------------------------------------------------------
// finalize: reduce A_coarse partials + threshold; L_spatial, lam
// ---------------------------------------------------------------------------
__global__ __launch_bounds__(256) void finalize_kernel(const float* __restrict__ Acp,
                                                       const float* __restrict__ loss,
                                                       const int* __restrict__ ec,
                                                       const float* __restrict__ sw,
                                                       const float* __restrict__ lamw,
                                                       float* __restrict__ out_At,
                                                       float* __restrict__ out_scalars) {
    int t = blockIdx.x * blockDim.x + threadIdx.x;
    if (t < KMAX * KMAX) {
        float s0 = 0.f, s1 = 0.f, s2 = 0.f, s3 = 0.f;
        for (int ch = 0; ch < NCHX; ch += 4) {
            s0 += Acp[(size_t)ch * 2500 + t];
            s1 += Acp[(size_t)(ch + 1) * 2500 + t];
            s2 += Acp[(size_t)(ch + 2) * 2500 + t];
            s3 += Acp[(size_t)(ch + 3) * 2500 + t];
        }
        float v = (s0 + s1) + (s2 + s3);
        out_At[t] = (v > THR) ? v : 0.f;
    }
    if (t == 0) {
        out_scalars[0] = sw[0] * loss[0] / (float)ec[0];     // L_spatial
        out_scalars[1] = 1.f / (1.f + expf(-lamw[0]));       // lam
    }
}

// ---------------------------------------------------------------------------
// launch
// ---------------------------------------------------------------------------
extern "C" void kernel_launch(void* const* d_in, const int* in_sizes, int n_in,
                              void* d_out, int out_size, void* d_ws, size_t ws_size,
                              hipStream_t stream) {
    const float* features = (const float*)d_in[0];
    const float* positions = (const float*)d_in[1];
    const float* lambda_w  = (const float*)d_in[2];
    const float* temp_w    = (const float*)d_in[3];
    const float* spatial_w = (const float*)d_in[4];
    const float* W1 = (const float*)d_in[5];
    const float* b1 = (const float*)d_in[6];
    const float* W2 = (const float*)d_in[7];
    const float* b2 = (const float*)d_in[8];

    float* out = (float*)d_out;
    // output layout: S [N*50] | X_t [50*512] | A_t [50*50] | L_spatial | lam
    float* out_S  = out;
    float* out_Xt = out + (size_t)N_PTS * KMAX;
    float* out_At = out_Xt + KMAX * FEAT;
    float* out_sc = out_At + KMAX * KMAX;

    // workspace layout (~66 MB total)
    char* ws = (char*)d_ws;
    size_t off = 0;
    auto alloc = [&](size_t bytes) { size_t o = off; off = (off + bytes + 255) & ~(size_t)255; return o; };
    u16*   fnh     = (u16*)  (ws + alloc((size_t)N_PTS * FEAT * 2));
    u16*   fnl     = (u16*)  (ws + alloc((size_t)N_PTS * FEAT * 2));
    u16*   fh      = (u16*)  (ws + alloc((size_t)N_PTS * FEAT * 2));
    u16*   fl      = (u16*)  (ws + alloc((size_t)N_PTS * FEAT * 2));
    float* p2      = (float*)(ws + alloc((size_t)N_PTS * 4));
    float* adjchnk = (float*)(ws + alloc((size_t)N_PTS * CW * 4));
    float* gval    = (float*)(ws + alloc((size_t)N_PTS * KNN * 4));
    int*   gidx    = (int*)  (ws + alloc((size_t)N_PTS * KNN * 4));
    int*   indeg   = (int*)  (ws + alloc((size_t)N_PTS * 4));
    int*   fillc   = (int*)  (ws + alloc((size_t)N_PTS * 4));
    int*   offs    = (int*)  (ws + alloc((size_t)(N_PTS + 1) * 4));
    float* dinv    = (float*)(ws + alloc((size_t)N_PTS * 4));
    int*   csc     = (int*)  (ws + alloc((size_t)N_PTS * KNN * 4));
    u16*   w1th    = (u16*)  (ws + alloc((size_t)HID * FEAT * 2));
    u16*   w1tl    = (u16*)  (ws + alloc((size_t)HID * FEAT * 2));
    u16*   w2th    = (u16*)  (ws + alloc((size_t)64 * HID * 2));
    u16*   w2tl    = (u16*)  (ws + alloc((size_t)64 * HID * 2));
    float* lossrow = (float*)(ws + alloc((size_t)N_PTS * 4));
    float* lossb   = (float*)(ws + alloc(4));
    int*   ecnt    = (int*)  (ws + alloc(4));

    // post-topk buffers overlaid into the dead adjchnk region (37.7 MB)
    char* ov = (char*)adjchnk;
    float* Z   = (float*)(ov);                                  // 6.29 MB
    u16*   hh  = (u16*)  (ov + 7 * 1024 * 1024);                // 3.15 MB
    u16*   hl  = (u16*)  (ov + 11 * 1024 * 1024);               // 3.15 MB
    float* Y   = (float*)(ov + 15 * 1024 * 1024);               // 1.23 MB
    float* AS  = (float*)(ov + 17 * 1024 * 1024);               // 1.23 MB
    float* Xtp = (float*)(ov + 19 * 1024 * 1024);               // 9.83 MB (96x50x512)
    float* Acp = (float*)(ov + 30 * 1024 * 1024);               // 0.96 MB (96x2500)

    // 1. init accumulators
    init_kernel<<<(N_PTS + 255) / 256, 256, 0, stream>>>(indeg, fillc, ecnt);
    // 2. normalize (emit bf16 hi/lo of fn and raw f) + p2 + weight transposes
    normalize_kernel<<<N_PTS, 64, 0, stream>>>(features, fnh, fnl, fh, fl);
    p2_kernel<<<(N_PTS + 255) / 256, 256, 0, stream>>>(positions, p2);
    w1t_split_kernel<<<HID, 256, 0, stream>>>(W1, w1th, w1tl);
    w2t_split_kernel<<<64, 256, 0, stream>>>(W2, w2th, w2tl);
    // 3. adj chunks (MFMA, 8-wave blocks) + LDS-staged running top-20 merge
    for (int c = 0; c < NCHUNK; c++) {
        gemm_adj_mfma_kernel<<<dim3(CW / 128, N_PTS / 128), 512, 0, stream>>>(
            fnh, fnl, positions, p2, lambda_w, temp_w, adjchnk, c * CW);
        topk_kernel<<<N_PTS / 4, 256, 0, stream>>>(adjchnk, gval, gidx, c * CW);
    }
    // 4. degrees / E, CSC offsets, CSC fill
    degree_kernel<<<(N_PTS * KNN) / 256, 256, 0, stream>>>(gval, gidx, indeg, ecnt);
    scan_kernel<<<1, 1024, 0, stream>>>(indeg, offs, dinv);
    fill_kernel<<<(N_PTS * KNN) / 256, 256, 0, stream>>>(gval, gidx, offs, fillc, csc);
    // 5. GCN layer 1: Z = X@W1 (MFMA) ; h = relu(agg(Z)+b1) -> bf16 split
    gemm_z_kernel<<<dim3(HID / 128, N_PTS / 128), 256, 0, stream>>>(fh, fl, w1th, w1tl, Z);
    agg1_kernel<<<N_PTS, HID, 0, stream>>>(Z, offs, csc, dinv, b1, hh, hl);
    // 6. GCN layer 2: Y = h@W2 (MFMA) ; s = agg(Y)+b2 ; S = softmax(s)
    gemm_y_kernel<<<N_PTS / 128, 256, 0, stream>>>(hh, hl, w2th, w2tl, Y);
    agg2_softmax_kernel<<<N_PTS / 4, 256, 0, stream>>>(Y, offs, csc, dinv, b2, out_S);
    // 7. AS = adj@S, per-row loss, loss reduce
    rowops_kernel<<<N_PTS / 4, 256, 0, stream>>>(out_S, gidx, gval, positions, p2, AS, lossrow);
    loss_reduce_kernel<<<1, 1024, 0, stream>>>(lossrow, lossb);
    // 8. coarsening via split-K partials (no atomics) + reduces
    coarseA_kernel<<<NCHX, 256, 0, stream>>>(out_S, AS, Acp);
    coarseX_kernel<<<NCHX * 8, 64, 0, stream>>>(out_S, features, Xtp);
    reduceX_kernel<<<(KMAX * FEAT + 255) / 256, 256, 0, stream>>>(Xtp, out_Xt);
    // 9. finalize: A_t reduce+threshold, scalars
    finalize_kernel<<<(KMAX * KMAX + 255) / 256, 256, 0, stream>>>(Acp, lossb, ecnt, spatial_w, lambda_w, out_At, out_sc);
}